// Round 1
// baseline (297.898 us; speedup 1.0000x reference)
//
#include <hip/hip_runtime.h>

#define BATCH 16384
#define EMB 64
#define LANES_PER_ROW 16   // 16 lanes x float4 = 64 floats = one embedding row

// One 16-lane group per output row. Lane s of the group loads float4 #s of the
// user row and movie row, accumulates a 4-wide partial dot, then the group
// reduces via wave shuffles (groups are lane-contiguous inside the 64-wide wave).
__global__ __launch_bounds__(256) void recsys_dot_kernel(
    const int* __restrict__ users,
    const int* __restrict__ movies,
    const float* __restrict__ user_table,
    const float* __restrict__ movie_table,
    float* __restrict__ out)
{
    const int tid  = blockIdx.x * blockDim.x + threadIdx.x;
    const int row  = tid / LANES_PER_ROW;       // output row index
    const int sub  = tid % LANES_PER_ROW;       // float4 slot within the row
    if (row >= BATCH) return;

    const int u = users[row];
    const int m = movies[row];

    const float4* __restrict__ urow = (const float4*)(user_table  + (long long)u * EMB);
    const float4* __restrict__ mrow = (const float4*)(movie_table + (long long)m * EMB);

    const float4 uv = urow[sub];
    const float4 mv = mrow[sub];

    float p = uv.x * mv.x + uv.y * mv.y + uv.z * mv.z + uv.w * mv.w;

    // Reduce across the 16 lanes of this group (contiguous lanes in the wave).
    p += __shfl_down(p, 8);
    p += __shfl_down(p, 4);
    p += __shfl_down(p, 2);
    p += __shfl_down(p, 1);

    if (sub == 0) out[row] = p;
}

extern "C" void kernel_launch(void* const* d_in, const int* in_sizes, int n_in,
                              void* d_out, int out_size, void* d_ws, size_t ws_size,
                              hipStream_t stream) {
    const int*   users       = (const int*)d_in[0];
    const int*   movies      = (const int*)d_in[1];
    const float* user_table  = (const float*)d_in[2];
    const float* movie_table = (const float*)d_in[3];
    float*       out         = (float*)d_out;

    const int threads = 256;
    const int total   = BATCH * LANES_PER_ROW;          // 16 lanes per row
    const int blocks  = (total + threads - 1) / threads; // 1024
    recsys_dot_kernel<<<blocks, threads, 0, stream>>>(users, movies, user_table, movie_table, out);
}

// Round 2
// 296.484 us; speedup vs baseline: 1.0048x; 1.0048x over previous
//
#include <hip/hip_runtime.h>

#define BATCH 16384
#define EMB 64
#define LANES_PER_ROW 8    // 8 lanes x (2 x float4) = 64 floats = one embedding row

// One 8-lane group per output row. Lane s loads float4 slots s and s+8 of both
// the user row and the movie row (each load instruction covers a contiguous
// 128 B across the group), accumulates an 8-wide partial dot, then the group
// reduces via wave shuffles (groups are lane-contiguous inside the 64-wide wave).
__global__ __launch_bounds__(256) void recsys_dot_kernel(
    const int* __restrict__ users,
    const int* __restrict__ movies,
    const float* __restrict__ user_table,
    const float* __restrict__ movie_table,
    float* __restrict__ out)
{
    const int tid  = blockIdx.x * blockDim.x + threadIdx.x;
    const int row  = tid >> 3;        // output row index (grid exactly covers BATCH)
    const int sub  = tid & 7;         // float4 slot within the row

    const int u = users[row];
    const int m = movies[row];

    const float4* __restrict__ urow = (const float4*)(user_table  + (long long)u * EMB);
    const float4* __restrict__ mrow = (const float4*)(movie_table + (long long)m * EMB);

    // Two independent load pairs per lane -> memory-level parallelism.
    const float4 uv0 = urow[sub];
    const float4 mv0 = mrow[sub];
    const float4 uv1 = urow[sub + 8];
    const float4 mv1 = mrow[sub + 8];

    float p = uv0.x * mv0.x + uv0.y * mv0.y + uv0.z * mv0.z + uv0.w * mv0.w
            + uv1.x * mv1.x + uv1.y * mv1.y + uv1.z * mv1.z + uv1.w * mv1.w;

    // Reduce across the 8 lanes of this group (contiguous lanes in the wave).
    p += __shfl_down(p, 4);
    p += __shfl_down(p, 2);
    p += __shfl_down(p, 1);

    if (sub == 0) out[row] = p;
}

extern "C" void kernel_launch(void* const* d_in, const int* in_sizes, int n_in,
                              void* d_out, int out_size, void* d_ws, size_t ws_size,
                              hipStream_t stream) {
    const int*   users       = (const int*)d_in[0];
    const int*   movies      = (const int*)d_in[1];
    const float* user_table  = (const float*)d_in[2];
    const float* movie_table = (const float*)d_in[3];
    float*       out         = (float*)d_out;

    const int threads = 256;
    const int total   = BATCH * LANES_PER_ROW;           // 8 lanes per row
    const int blocks  = total / threads;                 // 512, exact cover
    recsys_dot_kernel<<<blocks, threads, 0, stream>>>(users, movies, user_table, movie_table, out);
}